// Round 9
// baseline (424.353 us; speedup 1.0000x reference)
//
#include <hip/hip_runtime.h>
#include <hip/hip_bf16.h>

// Attention fwd: B=4 H=16 S=2048 D=64, fp32 in/out, softmax(QK^T/8)V
// Round 9: 32 q-rows per wave (2 q-groups share every K/V LDS fragment ->
// LDS reads per FLOP halved; LDS was the measured bottleneck). 256-thr
// blocks (4 waves), double-buffered LDS, counted vmcnt, 4 blocks/CU.

constexpr int Sdim = 2048;
constexpr int Ddim = 64;
constexpr int QBLK = 128;           // 4 waves x 32 q-rows
constexpr int KVBLK = 64;
constexpr int NBH = 64;             // B*H
constexpr int NT = Sdim / KVBLK;    // 32
constexpr int TILE_E = KVBLK * Ddim; // 4096 elems per K/V tile
constexpr float QSCALE = 0.125f * 1.44269504f; // 1/sqrt(64) * log2(e)
constexpr float DEFER_THR = 11.0f;  // log2 units: p <= 2^11

typedef __attribute__((ext_vector_type(8))) short short8;
typedef __attribute__((ext_vector_type(4))) float f32x4;
typedef __attribute__((ext_vector_type(4))) unsigned short ushort4v;
typedef __attribute__((ext_vector_type(4))) unsigned int uint4v;
typedef __attribute__((ext_vector_type(2))) unsigned int uint2v;

typedef __attribute__((address_space(1))) const unsigned int GU32;
typedef __attribute__((address_space(3))) unsigned int LU32;

__device__ __forceinline__ unsigned short f2bf(float f) {
    union { float f; unsigned int u; } v; v.f = f;
    unsigned int r = v.u + 0x7FFFu + ((v.u >> 16) & 1u);   // RNE
    return (unsigned short)(r >> 16);
}

__device__ __forceinline__ unsigned int cvt_pk_bf16(float lo, float hi) {
    unsigned int r;
    asm("v_cvt_pk_bf16_f32 %0, %1, %2" : "=v"(r) : "v"(lo), "v"(hi));
    return r;
}

__device__ __forceinline__ void gload_lds16(const unsigned short* g, unsigned short* l) {
    __builtin_amdgcn_global_load_lds((GU32*)g, (LU32*)l, 16, 0, 0);
}

// ---- merged pre-pass (proven round 8) ----
constexpr int KPB = (NBH * Sdim * Ddim) / 4 / 256;   // 8192
constexpr int VPB = NBH * NT;                        // 2048

__global__ __launch_bounds__(256)
void prep_kv(const float* __restrict__ Kg, const float* __restrict__ Vg,
             unsigned short* __restrict__ Kbf, unsigned short* __restrict__ Vtb) {
    __shared__ unsigned short Vl[KVBLK][Ddim + 4];
    if (blockIdx.x < KPB) {
        size_t idx = ((size_t)blockIdx.x * 256 + threadIdx.x) * 4;
        int c0 = (int)(idx & 63);
        size_t row = idx >> 6;
        int swz = ((int)row & 7) << 3;
        float4 f = *(const float4*)(Kg + idx);
        ushort4v h;
        h.x = f2bf(f.x); h.y = f2bf(f.y); h.z = f2bf(f.z); h.w = f2bf(f.w);
        *(ushort4v*)(Kbf + (row << 6) + (c0 ^ swz)) = h;
        return;
    }
    int bid = blockIdx.x - KPB;
    int bh = bid >> 5, t = bid & 31;
    const float* src = Vg + ((size_t)bh * Sdim + t * KVBLK) * Ddim;
    unsigned short* dst = Vtb + ((size_t)bh * NT + t) * TILE_E;
    {
        int kv = threadIdx.x >> 2;
        int dq = (threadIdx.x & 3) * 16;
#pragma unroll
        for (int i = 0; i < 4; ++i) {
            float4 f = *(const float4*)(src + (size_t)kv * Ddim + dq + 4 * i);
            ushort4v h;
            h.x = f2bf(f.x); h.y = f2bf(f.y); h.z = f2bf(f.z); h.w = f2bf(f.w);
            *(ushort4v*)&Vl[kv][dq + 4 * i] = h;
        }
    }
    __syncthreads();
    {
        int d  = threadIdx.x >> 2;
        int sc = (threadIdx.x & 3) * 16;
        int swzd = (d & 7) << 3;
#pragma unroll
        for (int u = 0; u < 4; ++u) {
            int s0 = sc + 4 * u;
            int kc = s0 >> 5, g = (s0 >> 3) & 3, h = (s0 >> 2) & 1;
            int kvb = 32 * kc + 16 * h + 4 * g;
            ushort4v o;
            o.x = Vl[kvb + 0][d]; o.y = Vl[kvb + 1][d];
            o.z = Vl[kvb + 2][d]; o.w = Vl[kvb + 3][d];
            *(ushort4v*)(dst + (size_t)d * KVBLK + (s0 ^ swzd)) = o;
        }
    }
}

// ================= fast main kernel =================
__global__ __launch_bounds__(256, 4)
void attn_fwd_fast(const float* __restrict__ Qg, const unsigned short* __restrict__ Kbf,
                   const unsigned short* __restrict__ Vtb, float* __restrict__ Og)
{
    __shared__ unsigned short Kt[2][TILE_E];   // [buf][kv*64+d], row-swizzled
    __shared__ unsigned short Vt[2][TILE_E];   // [buf][d*64+perm(kv)], row-swizzled

    const int tid = threadIdx.x;
    const int w   = tid >> 6;       // 0..3
    const int l   = tid & 63;
    const int g   = l >> 4;
    const int q   = l & 15;
    const int swz = (q & 7) << 3;

    const int bh = blockIdx.y;
    const size_t base = (size_t)bh * Sdim * Ddim;
    const int q0 = blockIdx.x * QBLK;

    const unsigned short* kbase = Kbf + base;
    const unsigned short* vbase = Vtb + base;
    const int eo = tid * 8;                  // 256 thr x 16B = 4KB per pass
    const int stoff = w * 512;               // wave-uniform LDS dest (elements)

    // Q fragments: 2 q-groups (rows w*32 + gg*16 + q), scale*log2e folded in
    short8 qf[2][2];
#pragma unroll
    for (int gg = 0; gg < 2; ++gg) {
        const float* qrow = Qg + base + (size_t)(q0 + w * 32 + gg * 16 + q) * Ddim;
#pragma unroll
        for (int kc = 0; kc < 2; ++kc) {
            float fv[8];
            *(float4*)(fv)     = *(const float4*)(qrow + kc * 32 + g * 8);
            *(float4*)(fv + 4) = *(const float4*)(qrow + kc * 32 + g * 8 + 4);
            short8 r;
#pragma unroll
            for (int j = 0; j < 8; ++j) r[j] = (short)f2bf(fv[j] * QSCALE);
            qf[gg][kc] = r;
        }
    }

    f32x4 o_[2][4];
#pragma unroll
    for (int gg = 0; gg < 2; ++gg)
#pragma unroll
        for (int dt = 0; dt < 4; ++dt)
#pragma unroll
            for (int r = 0; r < 4; ++r) o_[gg][dt][r] = 0.0f;
    float m_run[2] = {0.0f, 0.0f};
    float l_part[2] = {0.0f, 0.0f};

    // prologue: stage tile 0 into buf 0 (4 loads: K x2 passes, V x2 passes)
    gload_lds16(kbase + eo,        &Kt[0][0] + stoff);
    gload_lds16(kbase + 2048 + eo, &Kt[0][0] + 2048 + stoff);
    gload_lds16(vbase + eo,        &Vt[0][0] + stoff);
    gload_lds16(vbase + 2048 + eo, &Vt[0][0] + 2048 + stoff);

    for (int t = 0; t < NT; ++t) {
        const int cur = t & 1;
        if (t + 1 < NT) {
            const size_t toff = (size_t)(t + 1) * TILE_E + eo;
            unsigned short* kd = &Kt[cur ^ 1][0];
            unsigned short* vd = &Vt[cur ^ 1][0];
            gload_lds16(kbase + toff,        kd + stoff);
            gload_lds16(kbase + toff + 2048, kd + 2048 + stoff);
            gload_lds16(vbase + toff,        vd + stoff);
            gload_lds16(vbase + toff + 2048, vd + 2048 + stoff);
            asm volatile("s_waitcnt vmcnt(4)" ::: "memory");   // tile t done
        } else {
            asm volatile("s_waitcnt vmcnt(0)" ::: "memory");
        }
        __builtin_amdgcn_s_barrier();
        __builtin_amdgcn_sched_barrier(0);

        const unsigned short* kb = &Kt[cur][0];
        const unsigned short* vb = &Vt[cur][0];

        // S^T = mfma(K, Q) for both q-groups; each K frag feeds 2 MFMAs
        f32x4 sa[2][4];
#pragma unroll
        for (int gg = 0; gg < 2; ++gg)
#pragma unroll
            for (int nt = 0; nt < 4; ++nt)
#pragma unroll
                for (int r = 0; r < 4; ++r) sa[gg][nt][r] = -m_run[gg];
        __builtin_amdgcn_s_setprio(1);
#pragma unroll
        for (int kc = 0; kc < 2; ++kc)
#pragma unroll
            for (int nt = 0; nt < 4; ++nt) {
                const short8 kf = *(const short8*)(kb + (nt * 16 + q) * Ddim + ((kc * 32 + g * 8) ^ swz));
                sa[0][nt] = __builtin_amdgcn_mfma_f32_16x16x32_bf16(kf, qf[0][kc], sa[0][nt], 0, 0, 0);
                sa[1][nt] = __builtin_amdgcn_mfma_f32_16x16x32_bf16(kf, qf[1][kc], sa[1][nt], 0, 0, 0);
            }
        __builtin_amdgcn_s_setprio(0);

        // row max per group (values already shifted by -m_run)
        float mx[2];
#pragma unroll
        for (int gg = 0; gg < 2; ++gg) {
            f32x4 m4 = sa[gg][0];
#pragma unroll
            for (int nt = 1; nt < 4; ++nt)
#pragma unroll
                for (int r = 0; r < 4; ++r) m4[r] = fmaxf(m4[r], sa[gg][nt][r]);
            float m = fmaxf(fmaxf(m4[0], m4[1]), fmaxf(m4[2], m4[3]));
            m = fmaxf(m, __shfl_xor(m, 16));
            m = fmaxf(m, __shfl_xor(m, 32));
            mx[gg] = m;
        }

        uint4v pav[2][2];   // [gg][kc] -> PV A-fragment words
        if (__all(fmaxf(mx[0], mx[1]) <= DEFER_THR)) {
            // deferred: p = exp2(sa) directly, no rescale
#pragma unroll
            for (int gg = 0; gg < 2; ++gg) {
                float ts = 0.0f;
#pragma unroll
                for (int nt = 0; nt < 4; ++nt) {
                    float e0 = exp2f(sa[gg][nt][0]), e1 = exp2f(sa[gg][nt][1]);
                    float e2 = exp2f(sa[gg][nt][2]), e3 = exp2f(sa[gg][nt][3]);
                    ts += (e0 + e1) + (e2 + e3);
                    pav[gg][nt >> 1][(nt & 1) * 2 + 0] = cvt_pk_bf16(e0, e1);
                    pav[gg][nt >> 1][(nt & 1) * 2 + 1] = cvt_pk_bf16(e2, e3);
                }
                l_part[gg] += ts;
            }
        } else {
#pragma unroll
            for (int gg = 0; gg < 2; ++gg) {
                float m = mx[gg];
                float fr = exp2f(-m);
                m_run[gg] += m;
                float ts = 0.0f;
#pragma unroll
                for (int nt = 0; nt < 4; ++nt) {
                    float e0 = exp2f(sa[gg][nt][0] - m), e1 = exp2f(sa[gg][nt][1] - m);
                    float e2 = exp2f(sa[gg][nt][2] - m), e3 = exp2f(sa[gg][nt][3] - m);
                    ts += (e0 + e1) + (e2 + e3);
                    pav[gg][nt >> 1][(nt & 1) * 2 + 0] = cvt_pk_bf16(e0, e1);
                    pav[gg][nt >> 1][(nt & 1) * 2 + 1] = cvt_pk_bf16(e2, e3);
                }
                l_part[gg] = l_part[gg] * fr + ts;
                float frb[4];
#pragma unroll
                for (int r = 0; r < 4; ++r) frb[r] = __shfl(fr, 4 * g + r);
#pragma unroll
                for (int dt = 0; dt < 4; ++dt)
#pragma unroll
                    for (int r = 0; r < 4; ++r) o_[gg][dt][r] *= frb[r];
            }
        }

        // O += P V : each V frag feeds both q-groups
        __builtin_amdgcn_s_setprio(1);
#pragma unroll
        for (int kc = 0; kc < 2; ++kc) {
            const short8 pa0 = __builtin_bit_cast(short8, pav[0][kc]);
            const short8 pa1 = __builtin_bit_cast(short8, pav[1][kc]);
#pragma unroll
            for (int dt = 0; dt < 4; ++dt) {
                const short8 vf = *(const short8*)(vb + (dt * 16 + q) * Ddim + ((kc * 32 + g * 8) ^ swz));
                o_[0][dt] = __builtin_amdgcn_mfma_f32_16x16x32_bf16(pa0, vf, o_[0][dt], 0, 0, 0);
                o_[1][dt] = __builtin_amdgcn_mfma_f32_16x16x32_bf16(pa1, vf, o_[1][dt], 0, 0, 0);
            }
        }
        __builtin_amdgcn_s_setprio(0);

        if (t + 1 < NT) {
            __builtin_amdgcn_sched_barrier(0);
            __builtin_amdgcn_s_barrier();       // buf[cur] fully consumed
        }
    }

    // epilogue per group: reduce l partials, scale, store
#pragma unroll
    for (int gg = 0; gg < 2; ++gg) {
        float lp = l_part[gg];
        lp += __shfl_xor(lp, 16);
        lp += __shfl_xor(lp, 32);
        float inv = 1.0f / lp;
        float invb[4];
#pragma unroll
        for (int r = 0; r < 4; ++r) invb[r] = __shfl(inv, 4 * g + r);
#pragma unroll
        for (int r = 0; r < 4; ++r) {
            float* orow = Og + base + (size_t)(q0 + w * 32 + gg * 16 + 4 * g + r) * Ddim;
#pragma unroll
            for (int dt = 0; dt < 4; ++dt) orow[dt * 16 + q] = o_[gg][dt][r] * invb[r];
        }
    }
}

// ================= fallback (round-3 kernel, proven) =================
__global__ __launch_bounds__(256, 4)
void attn_fwd_slow(const float* __restrict__ Qg, const float* __restrict__ Kg,
                   const float* __restrict__ Vg, float* __restrict__ Og)
{
    __shared__ unsigned short Kts[KVBLK][Ddim];
    __shared__ unsigned short Vts[Ddim][KVBLK];
    __shared__ unsigned short Pt[4][16][KVBLK];

    const int tid = threadIdx.x;
    const int w   = tid >> 6;
    const int l   = tid & 63;
    const int g   = l >> 4;
    const int q   = l & 15;
    const int swz = (q & 7) << 3;

    const size_t base = (size_t)blockIdx.y * Sdim * Ddim;
    const int q0 = blockIdx.x * 64;

    short8 qf[2];
    {
        const float* qrow = Qg + base + (size_t)(q0 + w * 16 + q) * Ddim;
#pragma unroll
        for (int kc = 0; kc < 2; ++kc) {
            float fv[8];
            *(float4*)(fv)     = *(const float4*)(qrow + kc * 32 + g * 8);
            *(float4*)(fv + 4) = *(const float4*)(qrow + kc * 32 + g * 8 + 4);
            short8 r;
#pragma unroll
            for (int j = 0; j < 8; ++j) r[j] = (short)f2bf(fv[j] * QSCALE);
            qf[kc] = r;
        }
    }

    f32x4 o[4];
#pragma unroll
    for (int dt = 0; dt < 4; ++dt)
#pragma unroll
        for (int r = 0; r < 4; ++r) o[dt][r] = 0.0f;
    float m_run = -INFINITY, l_run = 0.0f;

    for (int t = 0; t < NT; ++t) {
        __syncthreads();
        {
            const float* Ksrc = Kg + base + (size_t)t * KVBLK * Ddim;
            const float* Vsrc = Vg + base + (size_t)t * KVBLK * Ddim;
#pragma unroll
            for (int it = 0; it < 4; ++it) {
                int idx = it * 1024 + tid * 4;
                int r = idx >> 6, c = idx & 63;
                float4 kf4 = *(const float4*)(Ksrc + idx);
                ushort4v hk;
                hk.x = f2bf(kf4.x); hk.y = f2bf(kf4.y);
                hk.z = f2bf(kf4.z); hk.w = f2bf(kf4.w);
                *(ushort4v*)&Kts[r][c ^ ((r & 7) << 3)] = hk;
            }
            {
                const int d = l;
                const int vswz = (d & 7) << 3;
#pragma unroll
                for (int i = 0; i < 4; ++i) {
                    int kv0 = w * 16 + i * 4;
                    float a0 = Vsrc[(size_t)(kv0 + 0) * Ddim + d];
                    float a1 = Vsrc[(size_t)(kv0 + 1) * Ddim + d];
                    float a2 = Vsrc[(size_t)(kv0 + 2) * Ddim + d];
                    float a3 = Vsrc[(size_t)(kv0 + 3) * Ddim + d];
                    ushort4v hv;
                    hv.x = f2bf(a0); hv.y = f2bf(a1);
                    hv.z = f2bf(a2); hv.w = f2bf(a3);
                    *(ushort4v*)&Vts[d][kv0 ^ vswz] = hv;
                }
            }
        }
        __syncthreads();

        f32x4 sa[4];
#pragma unroll
        for (int nt = 0; nt < 4; ++nt)
#pragma unroll
            for (int r = 0; r < 4; ++r) sa[nt][r] = 0.0f;
#pragma unroll
        for (int kc = 0; kc < 2; ++kc)
#pragma unroll
            for (int nt = 0; nt < 4; ++nt) {
                const short8 kf = *(const short8*)&Kts[nt * 16 + q][(kc * 32 + g * 8) ^ swz];
                sa[nt] = __builtin_amdgcn_mfma_f32_16x16x32_bf16(kf, qf[kc], sa[nt], 0, 0, 0);
            }

        float mx = sa[0][0];
#pragma unroll
        for (int nt = 0; nt < 4; ++nt)
#pragma unroll
            for (int r = 0; r < 4; ++r) mx = fmaxf(mx, sa[nt][r]);
        mx = fmaxf(mx, __shfl_xor(mx, 16));
        mx = fmaxf(mx, __shfl_xor(mx, 32));
        float mnew = fmaxf(m_run, mx);
        float fr = exp2f(m_run - mnew);
        m_run = mnew;

        float p[4][4];
        float s = 0.0f;
#pragma unroll
        for (int nt = 0; nt < 4; ++nt)
#pragma unroll
            for (int r = 0; r < 4; ++r) {
                float e = exp2f(sa[nt][r] - mnew);
                p[nt][r] = e; s += e;
            }
        s += __shfl_xor(s, 16);
        s += __shfl_xor(s, 32);
        l_run = l_run * fr + s;

#pragma unroll
        for (int nt = 0; nt < 4; ++nt) {
            uint2v pp;
            pp.x = cvt_pk_bf16(p[nt][0], p[nt][1]);
            pp.y = cvt_pk_bf16(p[nt][2], p[nt][3]);
            *(uint2v*)&Pt[w][q][(nt * 16 + 4 * g) ^ swz] = pp;
        }

        float frb[4];
#pragma unroll
        for (int r = 0; r < 4; ++r) frb[r] = __shfl(fr, 4 * g + r);
#pragma unroll
        for (int dt = 0; dt < 4; ++dt)
#pragma unroll
            for (int r = 0; r < 4; ++r) o[dt][r] *= frb[r];

#pragma unroll
        for (int kc = 0; kc < 2; ++kc) {
            const short8 pf = *(const short8*)&Pt[w][q][(kc * 32 + g * 8) ^ swz];
#pragma unroll
            for (int dt = 0; dt < 4; ++dt) {
                const short8 vf = *(const short8*)&Vts[dt * 16 + q][(kc * 32 + g * 8) ^ swz];
                o[dt] = __builtin_amdgcn_mfma_f32_16x16x32_bf16(pf, vf, o[dt], 0, 0, 0);
            }
        }
    }

    float inv = 1.0f / l_run;
    float invb[4];
#pragma unroll
    for (int r = 0; r < 4; ++r) invb[r] = __shfl(inv, 4 * g + r);
#pragma unroll
    for (int r = 0; r < 4; ++r) {
        float* orow = Og + base + (size_t)(q0 + w * 16 + 4 * g + r) * Ddim;
#pragma unroll
        for (int dt = 0; dt < 4; ++dt) orow[dt * 16 + q] = o[dt][r] * invb[r];
    }
}

extern "C" void kernel_launch(void* const* d_in, const int* in_sizes, int n_in,
                              void* d_out, int out_size, void* d_ws, size_t ws_size,
                              hipStream_t stream) {
    const float* Q = (const float*)d_in[0];
    const float* K = (const float*)d_in[1];
    const float* V = (const float*)d_in[2];
    float* O = (float*)d_out;
    const size_t elems = (size_t)NBH * Sdim * Ddim;          // 8.39M
    const size_t need  = elems * 2 * 2;                      // Kbf + Vtb, bf16
    if (ws_size >= need) {
        unsigned short* Kbf = (unsigned short*)d_ws;
        unsigned short* Vtb = Kbf + elems;
        prep_kv<<<dim3(KPB + VPB), dim3(256), 0, stream>>>(K, V, Kbf, Vtb);
        attn_fwd_fast<<<dim3(Sdim / QBLK, NBH), dim3(256), 0, stream>>>(Q, Kbf, Vtb, O);
    } else {
        attn_fwd_slow<<<dim3(Sdim / 64, NBH), dim3(256), 0, stream>>>(Q, K, V, O);
    }
}

// Round 11
// 262.526 us; speedup vs baseline: 1.6164x; 1.6164x over previous
//
#include <hip/hip_runtime.h>
#include <hip/hip_bf16.h>

// Attention fwd: B=4 H=16 S=2048 D=64, fp32 in/out, softmax(QK^T/8)V
// Round 10 (resubmit after infra timeout): round-8 skeleton (512 thr / 8
// waves, dbuf LDS, vmcnt(2)) with 32 q-rows per wave (2 q-groups share every
// K/V LDS fragment -> LDS reads per FLOP halved). launch_bounds(512,2):
// 256-VGPR ceiling, NO clamp-spill.

constexpr int Sdim = 2048;
constexpr int Ddim = 64;
constexpr int QBLK = 256;           // 8 waves x 32 q-rows
constexpr int KVBLK = 64;
constexpr int NBH = 64;             // B*H
constexpr int NT = Sdim / KVBLK;    // 32
constexpr int TILE_E = KVBLK * Ddim; // 4096 elems per K/V tile
constexpr float QSCALE = 0.125f * 1.44269504f; // 1/sqrt(64) * log2(e)
constexpr float DEFER_THR = 11.0f;  // log2 units: p <= 2^11

typedef __attribute__((ext_vector_type(8))) short short8;
typedef __attribute__((ext_vector_type(4))) float f32x4;
typedef __attribute__((ext_vector_type(4))) unsigned short ushort4v;
typedef __attribute__((ext_vector_type(4))) unsigned int uint4v;
typedef __attribute__((ext_vector_type(2))) unsigned int uint2v;

typedef __attribute__((address_space(1))) const unsigned int GU32;
typedef __attribute__((address_space(3))) unsigned int LU32;

__device__ __forceinline__ unsigned short f2bf(float f) {
    union { float f; unsigned int u; } v; v.f = f;
    unsigned int r = v.u + 0x7FFFu + ((v.u >> 16) & 1u);   // RNE
    return (unsigned short)(r >> 16);
}

__device__ __forceinline__ unsigned int cvt_pk_bf16(float lo, float hi) {
    unsigned int r;
    asm("v_cvt_pk_bf16_f32 %0, %1, %2" : "=v"(r) : "v"(lo), "v"(hi));
    return r;
}

__device__ __forceinline__ void gload_lds16(const unsigned short* g, unsigned short* l) {
    __builtin_amdgcn_global_load_lds((GU32*)g, (LU32*)l, 16, 0, 0);
}

// ---- merged pre-pass (proven round 8) ----
constexpr int KPB = (NBH * Sdim * Ddim) / 4 / 256;   // 8192
constexpr int VPB = NBH * NT;                        // 2048

__global__ __launch_bounds__(256)
void prep_kv(const float* __restrict__ Kg, const float* __restrict__ Vg,
             unsigned short* __restrict__ Kbf, unsigned short* __restrict__ Vtb) {
    __shared__ unsigned short Vl[KVBLK][Ddim + 4];
    if (blockIdx.x < KPB) {
        size_t idx = ((size_t)blockIdx.x * 256 + threadIdx.x) * 4;
        int c0 = (int)(idx & 63);
        size_t row = idx >> 6;
        int swz = ((int)row & 7) << 3;
        float4 f = *(const float4*)(Kg + idx);
        ushort4v h;
        h.x = f2bf(f.x); h.y = f2bf(f.y); h.z = f2bf(f.z); h.w = f2bf(f.w);
        *(ushort4v*)(Kbf + (row << 6) + (c0 ^ swz)) = h;
        return;
    }
    int bid = blockIdx.x - KPB;
    int bh = bid >> 5, t = bid & 31;
    const float* src = Vg + ((size_t)bh * Sdim + t * KVBLK) * Ddim;
    unsigned short* dst = Vtb + ((size_t)bh * NT + t) * TILE_E;
    {
        int kv = threadIdx.x >> 2;
        int dq = (threadIdx.x & 3) * 16;
#pragma unroll
        for (int i = 0; i < 4; ++i) {
            float4 f = *(const float4*)(src + (size_t)kv * Ddim + dq + 4 * i);
            ushort4v h;
            h.x = f2bf(f.x); h.y = f2bf(f.y); h.z = f2bf(f.z); h.w = f2bf(f.w);
            *(ushort4v*)&Vl[kv][dq + 4 * i] = h;
        }
    }
    __syncthreads();
    {
        int d  = threadIdx.x >> 2;
        int sc = (threadIdx.x & 3) * 16;
        int swzd = (d & 7) << 3;
#pragma unroll
        for (int u = 0; u < 4; ++u) {
            int s0 = sc + 4 * u;
            int kc = s0 >> 5, g = (s0 >> 3) & 3, h = (s0 >> 2) & 1;
            int kvb = 32 * kc + 16 * h + 4 * g;
            ushort4v o;
            o.x = Vl[kvb + 0][d]; o.y = Vl[kvb + 1][d];
            o.z = Vl[kvb + 2][d]; o.w = Vl[kvb + 3][d];
            *(ushort4v*)(dst + (size_t)d * KVBLK + (s0 ^ swzd)) = o;
        }
    }
}

// ================= fast main kernel =================
__global__ __launch_bounds__(512, 2)
void attn_fwd_fast(const float* __restrict__ Qg, const unsigned short* __restrict__ Kbf,
                   const unsigned short* __restrict__ Vtb, float* __restrict__ Og)
{
    __shared__ unsigned short Kt[2][TILE_E];   // [buf][kv*64 + swz(d)]
    __shared__ unsigned short Vt[2][TILE_E];   // [buf][d*64 + swz(perm(kv))]

    const int tid = threadIdx.x;
    const int w   = tid >> 6;       // 0..7
    const int l   = tid & 63;
    const int g   = l >> 4;
    const int q   = l & 15;
    const int swz = (q & 7) << 3;

    const int bh = blockIdx.y;
    const size_t base = (size_t)bh * Sdim * Ddim;
    const int q0 = blockIdx.x * QBLK;

    const unsigned short* kbase = Kbf + base;
    const unsigned short* vbase = Vtb + base;
    const int eo = tid * 8;                  // 512 thr x 16B = full 8KB tile
    const int stoff = w * 512;               // wave-uniform LDS dest (elements)

    // Q fragments: 2 q-groups (rows q0 + w*32 + gg*16 + q)
    short8 qf[2][2];
#pragma unroll
    for (int gg = 0; gg < 2; ++gg) {
        const float* qrow = Qg + base + (size_t)(q0 + w * 32 + gg * 16 + q) * Ddim;
#pragma unroll
        for (int kc = 0; kc < 2; ++kc) {
            float fv[8];
            *(float4*)(fv)     = *(const float4*)(qrow + kc * 32 + g * 8);
            *(float4*)(fv + 4) = *(const float4*)(qrow + kc * 32 + g * 8 + 4);
            short8 r;
#pragma unroll
            for (int j = 0; j < 8; ++j) r[j] = (short)f2bf(fv[j] * QSCALE);
            qf[gg][kc] = r;
        }
    }

    f32x4 o_[2][4];
#pragma unroll
    for (int gg = 0; gg < 2; ++gg)
#pragma unroll
        for (int dt = 0; dt < 4; ++dt)
#pragma unroll
            for (int r = 0; r < 4; ++r) o_[gg][dt][r] = 0.0f;
    float m_run[2] = {0.0f, 0.0f};
    float l_part[2] = {0.0f, 0.0f};

    // prologue: stage tile 0 into buf 0
    gload_lds16(kbase + eo, &Kt[0][0] + stoff);
    gload_lds16(vbase + eo, &Vt[0][0] + stoff);

    for (int t = 0; t < NT; ++t) {
        const int cur = t & 1;
        if (t + 1 < NT) {
            const size_t toff = (size_t)(t + 1) * TILE_E + eo;
            gload_lds16(kbase + toff, &Kt[cur ^ 1][0] + stoff);
            gload_lds16(vbase + toff, &Vt[cur ^ 1][0] + stoff);
            asm volatile("s_waitcnt vmcnt(2)" ::: "memory");   // tile t done
        } else {
            asm volatile("s_waitcnt vmcnt(0)" ::: "memory");
        }
        __builtin_amdgcn_s_barrier();
        __builtin_amdgcn_sched_barrier(0);

        const unsigned short* kb = &Kt[cur][0];
        const unsigned short* vb = &Vt[cur][0];

        // S^T = mfma(K, Q) for both q-groups; each K frag feeds 2 MFMAs
        f32x4 sa[2][4];
#pragma unroll
        for (int gg = 0; gg < 2; ++gg)
#pragma unroll
            for (int nt = 0; nt < 4; ++nt)
#pragma unroll
                for (int r = 0; r < 4; ++r) sa[gg][nt][r] = -m_run[gg];
        __builtin_amdgcn_s_setprio(1);
#pragma unroll
        for (int kc = 0; kc < 2; ++kc)
#pragma unroll
            for (int nt = 0; nt < 4; ++nt) {
                const short8 kf = *(const short8*)(kb + (nt * 16 + q) * Ddim + ((kc * 32 + g * 8) ^ swz));
                sa[0][nt] = __builtin_amdgcn_mfma_f32_16x16x32_bf16(kf, qf[0][kc], sa[0][nt], 0, 0, 0);
                sa[1][nt] = __builtin_amdgcn_mfma_f32_16x16x32_bf16(kf, qf[1][kc], sa[1][nt], 0, 0, 0);
            }
        __builtin_amdgcn_s_setprio(0);

        // row max per group (values already shifted by -m_run)
        float mx[2];
#pragma unroll
        for (int gg = 0; gg < 2; ++gg) {
            f32x4 m4 = sa[gg][0];
#pragma unroll
            for (int nt = 1; nt < 4; ++nt)
#pragma unroll
                for (int r = 0; r < 4; ++r) m4[r] = fmaxf(m4[r], sa[gg][nt][r]);
            float m = fmaxf(fmaxf(m4[0], m4[1]), fmaxf(m4[2], m4[3]));
            m = fmaxf(m, __shfl_xor(m, 16));
            m = fmaxf(m, __shfl_xor(m, 32));
            mx[gg] = m;
        }

        uint4v pav[2][2];   // [gg][kc] -> PV A-fragment words
        if (__all(fmaxf(mx[0], mx[1]) <= DEFER_THR)) {
            // deferred: p = exp2(sa) directly, no rescale
#pragma unroll
            for (int gg = 0; gg < 2; ++gg) {
                float ts = 0.0f;
#pragma unroll
                for (int nt = 0; nt < 4; ++nt) {
                    float e0 = exp2f(sa[gg][nt][0]), e1 = exp2f(sa[gg][nt][1]);
                    float e2 = exp2f(sa[gg][nt][2]), e3 = exp2f(sa[gg][nt][3]);
                    ts += (e0 + e1) + (e2 + e3);
                    pav[gg][nt >> 1][(nt & 1) * 2 + 0] = cvt_pk_bf16(e0, e1);
                    pav[gg][nt >> 1][(nt & 1) * 2 + 1] = cvt_pk_bf16(e2, e3);
                }
                l_part[gg] += ts;
            }
        } else {
#pragma unroll
            for (int gg = 0; gg < 2; ++gg) {
                float m = mx[gg];
                float fr = exp2f(-m);
                m_run[gg] += m;
                float ts = 0.0f;
#pragma unroll
                for (int nt = 0; nt < 4; ++nt) {
                    float e0 = exp2f(sa[gg][nt][0] - m), e1 = exp2f(sa[gg][nt][1] - m);
                    float e2 = exp2f(sa[gg][nt][2] - m), e3 = exp2f(sa[gg][nt][3] - m);
                    ts += (e0 + e1) + (e2 + e3);
                    pav[gg][nt >> 1][(nt & 1) * 2 + 0] = cvt_pk_bf16(e0, e1);
                    pav[gg][nt >> 1][(nt & 1) * 2 + 1] = cvt_pk_bf16(e2, e3);
                }
                l_part[gg] = l_part[gg] * fr + ts;
                float frb[4];
#pragma unroll
                for (int r = 0; r < 4; ++r) frb[r] = __shfl(fr, 4 * g + r);
#pragma unroll
                for (int dt = 0; dt < 4; ++dt)
#pragma unroll
                    for (int r = 0; r < 4; ++r) o_[gg][dt][r] *= frb[r];
            }
        }

        // O += P V : each V frag feeds both q-groups
        __builtin_amdgcn_s_setprio(1);
#pragma unroll
        for (int kc = 0; kc < 2; ++kc) {
            const short8 pa0 = __builtin_bit_cast(short8, pav[0][kc]);
            const short8 pa1 = __builtin_bit_cast(short8, pav[1][kc]);
#pragma unroll
            for (int dt = 0; dt < 4; ++dt) {
                const short8 vf = *(const short8*)(vb + (dt * 16 + q) * Ddim + ((kc * 32 + g * 8) ^ swz));
                o_[0][dt] = __builtin_amdgcn_mfma_f32_16x16x32_bf16(pa0, vf, o_[0][dt], 0, 0, 0);
                o_[1][dt] = __builtin_amdgcn_mfma_f32_16x16x32_bf16(pa1, vf, o_[1][dt], 0, 0, 0);
            }
        }
        __builtin_amdgcn_s_setprio(0);

        if (t + 1 < NT) {
            __builtin_amdgcn_sched_barrier(0);
            __builtin_amdgcn_s_barrier();       // buf[cur] fully consumed
        }
    }

    // epilogue per group: reduce l partials, scale, store
#pragma unroll
    for (int gg = 0; gg < 2; ++gg) {
        float lp = l_part[gg];
        lp += __shfl_xor(lp, 16);
        lp += __shfl_xor(lp, 32);
        float inv = 1.0f / lp;
        float invb[4];
#pragma unroll
        for (int r = 0; r < 4; ++r) invb[r] = __shfl(inv, 4 * g + r);
#pragma unroll
        for (int r = 0; r < 4; ++r) {
            float* orow = Og + base + (size_t)(q0 + w * 32 + gg * 16 + 4 * g + r) * Ddim;
#pragma unroll
            for (int dt = 0; dt < 4; ++dt) orow[dt * 16 + q] = o_[gg][dt][r] * invb[r];
        }
    }
}

// ================= fallback (round-3 kernel, proven) =================
__global__ __launch_bounds__(256, 4)
void attn_fwd_slow(const float* __restrict__ Qg, const float* __restrict__ Kg,
                   const float* __restrict__ Vg, float* __restrict__ Og)
{
    __shared__ unsigned short Kts[KVBLK][Ddim];
    __shared__ unsigned short Vts[Ddim][KVBLK];
    __shared__ unsigned short Pt[4][16][KVBLK];

    const int tid = threadIdx.x;
    const int w   = tid >> 6;
    const int l   = tid & 63;
    const int g   = l >> 4;
    const int q   = l & 15;
    const int swz = (q & 7) << 3;

    const size_t base = (size_t)blockIdx.y * Sdim * Ddim;
    const int q0 = blockIdx.x * 64;

    short8 qf[2];
    {
        const float* qrow = Qg + base + (size_t)(q0 + w * 16 + q) * Ddim;
#pragma unroll
        for (int kc = 0; kc < 2; ++kc) {
            float fv[8];
            *(float4*)(fv)     = *(const float4*)(qrow + kc * 32 + g * 8);
            *(float4*)(fv + 4) = *(const float4*)(qrow + kc * 32 + g * 8 + 4);
            short8 r;
#pragma unroll
            for (int j = 0; j < 8; ++j) r[j] = (short)f2bf(fv[j] * QSCALE);
            qf[kc] = r;
        }
    }

    f32x4 o[4];
#pragma unroll
    for (int dt = 0; dt < 4; ++dt)
#pragma unroll
        for (int r = 0; r < 4; ++r) o[dt][r] = 0.0f;
    float m_run = -INFINITY, l_run = 0.0f;

    for (int t = 0; t < NT; ++t) {
        __syncthreads();
        {
            const float* Ksrc = Kg + base + (size_t)t * KVBLK * Ddim;
            const float* Vsrc = Vg + base + (size_t)t * KVBLK * Ddim;
#pragma unroll
            for (int it = 0; it < 4; ++it) {
                int idx = it * 1024 + tid * 4;
                int r = idx >> 6, c = idx & 63;
                float4 kf4 = *(const float4*)(Ksrc + idx);
                ushort4v hk;
                hk.x = f2bf(kf4.x); hk.y = f2bf(kf4.y);
                hk.z = f2bf(kf4.z); hk.w = f2bf(kf4.w);
                *(ushort4v*)&Kts[r][c ^ ((r & 7) << 3)] = hk;
            }
            {
                const int d = l;
                const int vswz = (d & 7) << 3;
#pragma unroll
                for (int i = 0; i < 4; ++i) {
                    int kv0 = w * 16 + i * 4;
                    float a0 = Vsrc[(size_t)(kv0 + 0) * Ddim + d];
                    float a1 = Vsrc[(size_t)(kv0 + 1) * Ddim + d];
                    float a2 = Vsrc[(size_t)(kv0 + 2) * Ddim + d];
                    float a3 = Vsrc[(size_t)(kv0 + 3) * Ddim + d];
                    ushort4v hv;
                    hv.x = f2bf(a0); hv.y = f2bf(a1);
                    hv.z = f2bf(a2); hv.w = f2bf(a3);
                    *(ushort4v*)&Vts[d][kv0 ^ vswz] = hv;
                }
            }
        }
        __syncthreads();

        f32x4 sa[4];
#pragma unroll
        for (int nt = 0; nt < 4; ++nt)
#pragma unroll
            for (int r = 0; r < 4; ++r) sa[nt][r] = 0.0f;
#pragma unroll
        for (int kc = 0; kc < 2; ++kc)
#pragma unroll
            for (int nt = 0; nt < 4; ++nt) {
                const short8 kf = *(const short8*)&Kts[nt * 16 + q][(kc * 32 + g * 8) ^ swz];
                sa[nt] = __builtin_amdgcn_mfma_f32_16x16x32_bf16(kf, qf[kc], sa[nt], 0, 0, 0);
            }

        float mx = sa[0][0];
#pragma unroll
        for (int nt = 0; nt < 4; ++nt)
#pragma unroll
            for (int r = 0; r < 4; ++r) mx = fmaxf(mx, sa[nt][r]);
        mx = fmaxf(mx, __shfl_xor(mx, 16));
        mx = fmaxf(mx, __shfl_xor(mx, 32));
        float mnew = fmaxf(m_run, mx);
        float fr = exp2f(m_run - mnew);
        m_run = mnew;

        float p[4][4];
        float s = 0.0f;
#pragma unroll
        for (int nt = 0; nt < 4; ++nt)
#pragma unroll
            for (int r = 0; r < 4; ++r) {
                float e = exp2f(sa[nt][r] - mnew);
                p[nt][r] = e; s += e;
            }
        s += __shfl_xor(s, 16);
        s += __shfl_xor(s, 32);
        l_run = l_run * fr + s;

#pragma unroll
        for (int nt = 0; nt < 4; ++nt) {
            uint2v pp;
            pp.x = cvt_pk_bf16(p[nt][0], p[nt][1]);
            pp.y = cvt_pk_bf16(p[nt][2], p[nt][3]);
            *(uint2v*)&Pt[w][q][(nt * 16 + 4 * g) ^ swz] = pp;
        }

        float frb[4];
#pragma unroll
        for (int r = 0; r < 4; ++r) frb[r] = __shfl(fr, 4 * g + r);
#pragma unroll
        for (int dt = 0; dt < 4; ++dt)
#pragma unroll
            for (int r = 0; r < 4; ++r) o[dt][r] *= frb[r];

#pragma unroll
        for (int kc = 0; kc < 2; ++kc) {
            const short8 pf = *(const short8*)&Pt[w][q][(kc * 32 + g * 8) ^ swz];
#pragma unroll
            for (int dt = 0; dt < 4; ++dt) {
                const short8 vf = *(const short8*)&Vts[dt * 16 + q][(kc * 32 + g * 8) ^ swz];
                o[dt] = __builtin_amdgcn_mfma_f32_16x16x32_bf16(pf, vf, o[dt], 0, 0, 0);
            }
        }
    }

    float inv = 1.0f / l_run;
    float invb[4];
#pragma unroll
    for (int r = 0; r < 4; ++r) invb[r] = __shfl(inv, 4 * g + r);
#pragma unroll
    for (int r = 0; r < 4; ++r) {
        float* orow = Og + base + (size_t)(q0 + w * 16 + 4 * g + r) * Ddim;
#pragma unroll
        for (int dt = 0; dt < 4; ++dt) orow[dt * 16 + q] = o[dt][r] * invb[r];
    }
}

extern "C" void kernel_launch(void* const* d_in, const int* in_sizes, int n_in,
                              void* d_out, int out_size, void* d_ws, size_t ws_size,
                              hipStream_t stream) {
    const float* Q = (const float*)d_in[0];
    const float* K = (const float*)d_in[1];
    const float* V = (const float*)d_in[2];
    float* O = (float*)d_out;
    const size_t elems = (size_t)NBH * Sdim * Ddim;          // 8.39M
    const size_t need  = elems * 2 * 2;                      // Kbf + Vtb, bf16
    if (ws_size >= need) {
        unsigned short* Kbf = (unsigned short*)d_ws;
        unsigned short* Vtb = Kbf + elems;
        prep_kv<<<dim3(KPB + VPB), dim3(256), 0, stream>>>(K, V, Kbf, Vtb);
        attn_fwd_fast<<<dim3(Sdim / QBLK, NBH), dim3(512), 0, stream>>>(Q, Kbf, Vtb, O);
    } else {
        attn_fwd_slow<<<dim3(Sdim / 64, NBH), dim3(256), 0, stream>>>(Q, K, V, O);
    }
}